// Round 1
// baseline (79.159 us; speedup 1.0000x reference)
//
#include <hip/hip_runtime.h>
#include <math.h>

#define BB 16
#define HH 256
#define WW 256
#define NPIX (BB*HH*WW)
#define CH 16          // 16-row chunks per column
#define RPC 16
#define ROWS 8         // rows per block
#define NRB (BB*HH/ROWS)       // 512 blocks
#define PADW 4
#define GSTRIDE (WW + 2*PADW)  // 264 floats

// ws layout:
//   float    partials[NRB*8]  (16 KB)  per-block {sp,st,spt,sbce,sphip,amax,-,-}
//   unsigned flag              (4 B)   arrival counter, memset to 0 per launch

// Single fused kernel: per-block LDS rebuild of the zero-bitmasks (targ is
// L2-resident at 4 MB, 32x re-read = 128 MB of L2 traffic ~ 4 us), then the
// EDT window pass + loss partials, then last-block-done final reduction.
__global__ __launch_bounds__(256) void fused_kernel(const float* __restrict__ pred,
                                                    const float4* __restrict__ targ4,
                                                    float* __restrict__ partials,
                                                    unsigned* __restrict__ flag,
                                                    float* __restrict__ out) {
    int g = blockIdx.x;
    int b = g >> 5;                 // 32 blocks per image
    int r0 = (g & 31) << 3;         // first row-in-image (multiple of 8)
    int C = r0 >> 4;                // chunk containing all 8 rows
    int rb0 = r0 & 15;
    int j = threadIdx.x;

    __shared__ unsigned short zbS[CH][WW];   // 8 KB: bit r of zbS[c][j] = (targ[b,c*16+r,j]==0)
    __shared__ float gg[ROWS][2][GSTRIDE];   // [0,4) pad | data [4,260) | [260,264) pad
    __shared__ float red[4][8];
    __shared__ float arrF[256][3];
    __shared__ float bnd[BB];
    __shared__ float wred[4][4];
    __shared__ unsigned lastBlk;

    // ---- Phase A: rebuild zero-bitmasks for image b into LDS ----
    // 1024 tasks (chunk c, float4-colgroup q); 4 tasks/thread; coalesced 1 KB rows/wave.
    const float4* img = targ4 + (size_t)b * HH * (WW / 4);
    #pragma unroll
    for (int k = 0; k < 4; ++k) {
        int T = (k << 8) + j;
        int c = T >> 6, q = T & 63;
        const float4* m = img + (c * RPC) * (WW / 4) + q;
        unsigned z0 = 0, z1 = 0, z2 = 0, z3 = 0;
        #pragma unroll
        for (int r = 0; r < RPC; ++r) {
            float4 v = m[r * (WW / 4)];
            if (v.x == 0.0f) z0 |= 1u << r;
            if (v.y == 0.0f) z1 |= 1u << r;
            if (v.z == 0.0f) z2 |= 1u << r;
            if (v.w == 0.0f) z3 |= 1u << r;
        }
        ushort4 o;
        o.x = (unsigned short)z0; o.y = (unsigned short)z1;
        o.z = (unsigned short)z2; o.w = (unsigned short)z3;
        *reinterpret_cast<ushort4*>(&zbS[c][q << 2]) = o;
    }
    if (j < 2 * ROWS * 2 * PADW) {           // 128 pad slots of gg
        int r = j >> 4, f = (j >> 3) & 1, p = j & 7;
        gg[r][f][(p < PADW) ? p : (WW + p)] = 1e30f;
    }
    __syncthreads();

    // ---- Phase B: column-EDT carries from LDS masks ----
    int la0 = -1, la1 = -1;         // last zero strictly above chunk C (flavor 0/1)
    int fb0 = 100000, fb1 = 100000; // first zero strictly below chunk C
    unsigned zoc = 0;
    #pragma unroll
    for (int c = 0; c < CH; ++c) {
        unsigned z = (unsigned)zbS[c][j];
        unsigned zi = (~z) & 0xFFFFu;
        if (c < C) {
            if (z)  la0 = (c << 4) + (31 - __clz(z));
            if (zi) la1 = (c << 4) + (31 - __clz(zi));
        } else if (c > C) {
            if (z  && fb0 == 100000) fb0 = (c << 4) + (__ffs(z) - 1);
            if (zi && fb1 == 100000) fb1 = (c << 4) + (__ffs(zi) - 1);
        } else {
            zoc = z;
        }
    }
    unsigned zoc1 = (~zoc) & 0xFFFFu;

    float x[ROWS];
    #pragma unroll
    for (int r = 0; r < ROWS; ++r)
        x[r] = pred[(((b << 8) + (r0 + r)) << 8) + j];

    #pragma unroll
    for (int r = 0; r < ROWS; ++r) {
        int rb = rb0 + r;
        int i = r0 + r;
        unsigned below = zoc & ((2u << rb) - 1u);
        int lz = below ? ((C << 4) + (31 - __clz(below))) : la0;
        unsigned above = zoc & (0xFFFFu & ~((1u << rb) - 1u));
        int fz = above ? ((C << 4) + (__ffs(above) - 1)) : fb0;
        int da = (lz < 0) ? 100000 : (i - lz);
        int d0 = min(min(da, fz - i), 512);
        float f0 = (float)d0;
        gg[r][0][PADW + j] = f0 * f0;
        unsigned below1 = zoc1 & ((2u << rb) - 1u);
        int lz1 = below1 ? ((C << 4) + (31 - __clz(below1))) : la1;
        unsigned above1 = zoc1 & (0xFFFFu & ~((1u << rb) - 1u));
        int fz1 = above1 ? ((C << 4) + (__ffs(above1) - 1)) : fb1;
        int da1 = (lz1 < 0) ? 100000 : (i - lz1);
        int d1v = min(min(da1, fz1 - i), 512);
        float f1 = (float)d1v;
        gg[r][1][PADW + j] = f1 * f1;
    }
    __syncthreads();

    float sp = 0.f, st = 0.f, spt = 0.f, sbce = 0.f, sphip = 0.f, amax = 0.f;
    #pragma unroll
    for (int r = 0; r < ROWS; ++r) {
        int rb = rb0 + r;
        bool msk = (((zoc >> rb) & 1u) == 0u);    // mask nonzero at this pixel
        const float* bsel = &gg[r][msk ? 0 : 1][0];
        float best = 1e30f;
        #pragma unroll
        for (int c = 0; c <= 2 * PADW; ++c) {
            float Cc = (float)((PADW - c) * (PADW - c));   // == (j-k)^2, k = j-4+c
            best = fminf(best, bsel[j + c] + Cc);
        }
        if (__any(best > 25.0f)) {                // exact fallback (astronomically rare)
            const float* bs = bsel + PADW;
            for (int k = 0; k < WW; ++k) {
                float df = (float)(j - k);
                best = fminf(best, bs[k] + df * df);
            }
        }
        float dd = sqrtf(best);
        float phi = msk ? -dd : dd;               // phi = dist_out - dist_in
        float xr = x[r];
        float ax = fabsf(xr);
        float q = __expf(-ax);
        float pa = 1.0f / (1.0f + q);             // sigmoid(|x|)
        float p = (xr >= 0.0f) ? pa : q * pa;     // sigmoid(x)
        sp += p;
        st += msk ? 1.0f : 0.0f;
        spt += msk ? p : 0.0f;
        sbce += fmaxf(xr, 0.0f) - (msk ? xr : 0.0f) - __logf(pa);  // log1p(e^-|x|) = -log(pa)
        sphip += phi * p;
        amax = fmaxf(amax, fabsf(phi));
    }

    #pragma unroll
    for (int off = 32; off > 0; off >>= 1) {
        sp    += __shfl_down(sp,    off, 64);
        st    += __shfl_down(st,    off, 64);
        spt   += __shfl_down(spt,   off, 64);
        sbce  += __shfl_down(sbce,  off, 64);
        sphip += __shfl_down(sphip, off, 64);
        amax   = fmaxf(amax,  __shfl_down(amax,  off, 64));
    }
    int lane = j & 63, wv = j >> 6;
    if (lane == 0) {
        red[wv][0] = sp; red[wv][1] = st; red[wv][2] = spt; red[wv][3] = sbce;
        red[wv][4] = sphip; red[wv][5] = amax;
    }
    __syncthreads();

    // ---- Completion protocol: write record, count arrivals, last block reduces ----
    if (j == 0) {
        float* o = partials + (g << 3);
        #pragma unroll
        for (int q2 = 0; q2 < 5; ++q2)
            o[q2] = red[0][q2] + red[1][q2] + red[2][q2] + red[3][q2];
        o[5] = fmaxf(fmaxf(red[0][5], red[1][5]), fmaxf(red[2][5], red[3][5]));
        __builtin_amdgcn_fence(__ATOMIC_RELEASE, "agent");   // flush L2 (cross-XCD visibility)
        unsigned prev = atomicAdd(flag, 1u);                  // device-scope by default
        lastBlk = (prev == (unsigned)(NRB - 1)) ? 1u : 0u;
    }
    __syncthreads();
    if (lastBlk) {
        __builtin_amdgcn_fence(__ATOMIC_ACQUIRE, "agent");   // invalidate stale L1/L2 lines
        // ---- final reduction: identical op order to the previous final_kernel ----
        int t = j;
        float s0 = 0.f, s1 = 0.f, s2 = 0.f, s3 = 0.f, s4 = 0.f, m5 = 0.f;
        #pragma unroll
        for (int e = 0; e < 2; ++e) {
            const float* rec = partials + (((t << 1) + e) << 3);
            s0 += rec[0]; s1 += rec[1]; s2 += rec[2]; s3 += rec[3];
            s4 += rec[4];
            m5 = fmaxf(m5, rec[5]);
        }
        arrF[t][0] = s4; arrF[t][1] = m5; arrF[t][2] = s1;   // sphip, amax, st (per-image pieces)
        __syncthreads();
        if (t < 16) {
            float Sb = 0.f, Mb = 0.f, STb = 0.f;
            for (int e = 0; e < 16; ++e) {
                Sb += arrF[t * 16 + e][0];
                Mb = fmaxf(Mb, arrF[t * 16 + e][1]);
                STb += arrF[t * 16 + e][2];
            }
            bnd[t] = (STb > 0.0f) ? (Sb / (Mb + 1e-8f)) : 0.0f;   // jnp.any(mask>0) guard
        }
        #pragma unroll
        for (int off = 32; off > 0; off >>= 1) {
            s0 += __shfl_down(s0, off, 64);
            s1 += __shfl_down(s1, off, 64);
            s2 += __shfl_down(s2, off, 64);
            s3 += __shfl_down(s3, off, 64);
        }
        int lane2 = t & 63, wv2 = t >> 6;
        if (lane2 == 0) { wred[wv2][0] = s0; wred[wv2][1] = s1; wred[wv2][2] = s2; wred[wv2][3] = s3; }
        __syncthreads();
        if (t == 0) {
            float sp2   = wred[0][0] + wred[1][0] + wred[2][0] + wred[3][0];
            float st2   = wred[0][1] + wred[1][1] + wred[2][1] + wred[3][1];
            float spt2  = wred[0][2] + wred[1][2] + wred[2][2] + wred[3][2];
            float sbce2 = wred[0][3] + wred[1][3] + wred[2][3] + wred[3][3];
            float sbnd = 0.f;
            #pragma unroll
            for (int bb2 = 0; bb2 < BB; ++bb2) sbnd += bnd[bb2];
            float dice = 1.0f - (2.0f * spt2 + 1e-6f) / (sp2 + st2 + 1e-6f);
            float invN = 1.0f / (float)NPIX;
            float boundary = sbnd * invN;
            float bce = sbce2 * invN;
            float alpha = 0.005f;
            float beta = 0.6f - alpha;      // 0.595
            out[0] = (1.0f - beta) * dice + beta * boundary + 0.4f * bce;
        }
    }
}

extern "C" void kernel_launch(void* const* d_in, const int* in_sizes, int n_in,
                              void* d_out, int out_size, void* d_ws, size_t ws_size,
                              hipStream_t stream) {
    (void)in_sizes; (void)n_in; (void)out_size; (void)ws_size;
    const float* pred = (const float*)d_in[0];
    const float* targ = (const float*)d_in[1];
    float* partials = (float*)d_ws;                                    // 16 KB
    unsigned* flag = (unsigned*)((char*)d_ws + NRB * 8 * sizeof(float));

    hipMemsetAsync(flag, 0, sizeof(unsigned), stream);   // reset arrival counter (4 B, ~2 us)
    fused_kernel<<<NRB, 256, 0, stream>>>(pred, (const float4*)targ, partials, flag, (float*)d_out);
}

// Round 2
// 75.442 us; speedup vs baseline: 1.0493x; 1.0493x over previous
//
#include <hip/hip_runtime.h>
#include <math.h>

#define BB 16
#define HH 256
#define WW 256
#define NPIX (BB*HH*WW)
#define CH 16          // 16-row chunks per column
#define RPC 16
#define ROWS 8         // rows per rowmin block
#define NRB (BB*HH/ROWS)       // 512 rowmin blocks
#define PADW 4
#define GSTRIDE (WW + 2*PADW)  // 264 floats

// ws layout:
//   ushort zb[BB*CH*WW]   (128 KB)  bit r of zb[b,c,j] = (targ[b, c*16+r, j] == 0)
//   float  partials[NRB*8] (16 KB)  per-block {sp,st,spt,sbce,sphip,amax,-,-}
//   unsigned flag          (4 B)    arrival counter (reset by zbuild, no memset dispatch)

// targ -> zero bitmasks. 256 blocks (one 16-row chunk) x 64 threads (4 cols each).
// Block 0 lane 0 also resets the completion counter for the next dispatch
// (kernel-boundary release makes it visible to rowmin_fused).
__global__ __launch_bounds__(64) void zbuild_kernel(const float4* __restrict__ targ4,
                                                    ushort4* __restrict__ zb4,
                                                    unsigned* __restrict__ flag) {
    int blk = blockIdx.x;                 // b*16 + ch ; row offset = blk*16
    int t = threadIdx.x;
    if (blk == 0 && t == 0) *flag = 0u;
    const float4* m = targ4 + (size_t)blk * RPC * (WW / 4) + t;
    unsigned z0 = 0, z1 = 0, z2 = 0, z3 = 0;
    #pragma unroll
    for (int r = 0; r < RPC; ++r) {
        float4 v = m[r * (WW / 4)];
        if (v.x == 0.0f) z0 |= 1u << r;
        if (v.y == 0.0f) z1 |= 1u << r;
        if (v.z == 0.0f) z2 |= 1u << r;
        if (v.w == 0.0f) z3 |= 1u << r;
    }
    ushort4 o;
    o.x = (unsigned short)z0; o.y = (unsigned short)z1;
    o.z = (unsigned short)z2; o.w = (unsigned short)z3;
    zb4[blk * (WW / 4) + t] = o;
}

// Fused EDT pass2 + loss partials + last-block final reduction.
// One block per 8 rows. Column-EDT derived in-register from streamed bitmasks;
// windowed exact min (|j-k|<=4, bound 25) with per-wave full-scan fallback.
// Completion: each block publishes its record, fences, bumps the arrival
// counter; the 512th arriver runs the exact final reduction (identical op
// order to the standalone final_kernel -> bit-identical result).
__global__ __launch_bounds__(256) void rowmin_fused_kernel(const unsigned short* __restrict__ zb,
                                                           const float* __restrict__ pred,
                                                           float* __restrict__ partials,
                                                           unsigned* __restrict__ flag,
                                                           float* __restrict__ out) {
    int g = blockIdx.x;
    int b = g >> 5;                 // 32 blocks per image
    int r0 = (g & 31) << 3;         // first row-in-image (multiple of 8)
    int C = r0 >> 4;                // chunk containing all 8 rows
    int rb0 = r0 & 15;
    int j = threadIdx.x;

    // stream 16 chunk masks: carries + own-chunk mask, no indexed register array
    int la0 = -1, la1 = -1;         // last zero strictly above chunk C (flavor 0/1)
    int fb0 = 100000, fb1 = 100000; // first zero strictly below chunk C
    unsigned zoc = 0;
    #pragma unroll
    for (int c = 0; c < CH; ++c) {
        unsigned z = (unsigned)zb[((b * CH + c) << 8) + j];
        unsigned zi = (~z) & 0xFFFFu;
        if (c < C) {
            if (z)  la0 = (c << 4) + (31 - __clz(z));
            if (zi) la1 = (c << 4) + (31 - __clz(zi));
        } else if (c > C) {
            if (z  && fb0 == 100000) fb0 = (c << 4) + (__ffs(z) - 1);
            if (zi && fb1 == 100000) fb1 = (c << 4) + (__ffs(zi) - 1);
        } else {
            zoc = z;
        }
    }
    unsigned zoc1 = (~zoc) & 0xFFFFu;

    float x[ROWS];
    #pragma unroll
    for (int r = 0; r < ROWS; ++r)
        x[r] = pred[(((b << 8) + (r0 + r)) << 8) + j];

    __shared__ float gg[ROWS][2][GSTRIDE];   // [0,4) pad | data [4,260) | [260,264) pad
    __shared__ float red[4][8];
    __shared__ float arrF[256][3];
    __shared__ float bnd[BB];
    __shared__ float wred[4][4];
    __shared__ unsigned lastBlk;
    if (j < 2 * ROWS * 2 * PADW) {           // 128 pad slots
        int r = j >> 4, f = (j >> 3) & 1, p = j & 7;
        gg[r][f][(p < PADW) ? p : (WW + p)] = 1e30f;
    }

    #pragma unroll
    for (int r = 0; r < ROWS; ++r) {
        int rb = rb0 + r;
        int i = r0 + r;
        unsigned below = zoc & ((2u << rb) - 1u);
        int lz = below ? ((C << 4) + (31 - __clz(below))) : la0;
        unsigned above = zoc & (0xFFFFu & ~((1u << rb) - 1u));
        int fz = above ? ((C << 4) + (__ffs(above) - 1)) : fb0;
        int da = (lz < 0) ? 100000 : (i - lz);
        int d0 = min(min(da, fz - i), 512);
        float f0 = (float)d0;
        gg[r][0][PADW + j] = f0 * f0;
        unsigned below1 = zoc1 & ((2u << rb) - 1u);
        int lz1 = below1 ? ((C << 4) + (31 - __clz(below1))) : la1;
        unsigned above1 = zoc1 & (0xFFFFu & ~((1u << rb) - 1u));
        int fz1 = above1 ? ((C << 4) + (__ffs(above1) - 1)) : fb1;
        int da1 = (lz1 < 0) ? 100000 : (i - lz1);
        int d1v = min(min(da1, fz1 - i), 512);
        float f1 = (float)d1v;
        gg[r][1][PADW + j] = f1 * f1;
    }
    __syncthreads();

    float sp = 0.f, st = 0.f, spt = 0.f, sbce = 0.f, sphip = 0.f, amax = 0.f;
    #pragma unroll
    for (int r = 0; r < ROWS; ++r) {
        int rb = rb0 + r;
        bool msk = (((zoc >> rb) & 1u) == 0u);    // mask nonzero at this pixel
        const float* bsel = &gg[r][msk ? 0 : 1][0];
        float best = 1e30f;
        #pragma unroll
        for (int c = 0; c <= 2 * PADW; ++c) {
            float Cc = (float)((PADW - c) * (PADW - c));   // == (j-k)^2, k = j-4+c
            best = fminf(best, bsel[j + c] + Cc);
        }
        if (__any(best > 25.0f)) {                // exact fallback (astronomically rare)
            const float* bs = bsel + PADW;
            for (int k = 0; k < WW; ++k) {
                float df = (float)(j - k);
                best = fminf(best, bs[k] + df * df);
            }
        }
        float dd = sqrtf(best);
        float phi = msk ? -dd : dd;               // phi = dist_out - dist_in
        float xr = x[r];
        float ax = fabsf(xr);
        float q = __expf(-ax);
        float pa = 1.0f / (1.0f + q);             // sigmoid(|x|)
        float p = (xr >= 0.0f) ? pa : q * pa;     // sigmoid(x)
        sp += p;
        st += msk ? 1.0f : 0.0f;
        spt += msk ? p : 0.0f;
        sbce += fmaxf(xr, 0.0f) - (msk ? xr : 0.0f) - __logf(pa);  // log1p(e^-|x|) = -log(pa)
        sphip += phi * p;
        amax = fmaxf(amax, fabsf(phi));
    }

    #pragma unroll
    for (int off = 32; off > 0; off >>= 1) {
        sp    += __shfl_down(sp,    off, 64);
        st    += __shfl_down(st,    off, 64);
        spt   += __shfl_down(spt,   off, 64);
        sbce  += __shfl_down(sbce,  off, 64);
        sphip += __shfl_down(sphip, off, 64);
        amax   = fmaxf(amax,  __shfl_down(amax,  off, 64));
    }
    int lane = j & 63, wv = j >> 6;
    if (lane == 0) {
        red[wv][0] = sp; red[wv][1] = st; red[wv][2] = spt; red[wv][3] = sbce;
        red[wv][4] = sphip; red[wv][5] = amax;
    }
    __syncthreads();

    // ---- Completion protocol (verified round 1, absmax 0.0) ----
    if (j == 0) {
        float* o = partials + (g << 3);
        #pragma unroll
        for (int q2 = 0; q2 < 5; ++q2)
            o[q2] = red[0][q2] + red[1][q2] + red[2][q2] + red[3][q2];
        o[5] = fmaxf(fmaxf(red[0][5], red[1][5]), fmaxf(red[2][5], red[3][5]));
        __builtin_amdgcn_fence(__ATOMIC_RELEASE, "agent");   // cross-XCD visibility
        unsigned prev = atomicAdd(flag, 1u);                  // device-scope by default
        lastBlk = (prev == (unsigned)(NRB - 1)) ? 1u : 0u;
    }
    __syncthreads();
    if (lastBlk) {
        __builtin_amdgcn_fence(__ATOMIC_ACQUIRE, "agent");   // drop stale lines
        // ---- final reduction: identical op order to the standalone final_kernel ----
        int t = j;
        float s0 = 0.f, s1 = 0.f, s2 = 0.f, s3 = 0.f, s4 = 0.f, m5 = 0.f;
        #pragma unroll
        for (int e = 0; e < 2; ++e) {
            const float* rec = partials + (((t << 1) + e) << 3);
            s0 += rec[0]; s1 += rec[1]; s2 += rec[2]; s3 += rec[3];
            s4 += rec[4];
            m5 = fmaxf(m5, rec[5]);
        }
        arrF[t][0] = s4; arrF[t][1] = m5; arrF[t][2] = s1;   // sphip, amax, st (per-image)
        __syncthreads();
        if (t < 16) {
            float Sb = 0.f, Mb = 0.f, STb = 0.f;
            for (int e = 0; e < 16; ++e) {
                Sb += arrF[t * 16 + e][0];
                Mb = fmaxf(Mb, arrF[t * 16 + e][1]);
                STb += arrF[t * 16 + e][2];
            }
            bnd[t] = (STb > 0.0f) ? (Sb / (Mb + 1e-8f)) : 0.0f;   // jnp.any(mask>0) guard
        }
        #pragma unroll
        for (int off = 32; off > 0; off >>= 1) {
            s0 += __shfl_down(s0, off, 64);
            s1 += __shfl_down(s1, off, 64);
            s2 += __shfl_down(s2, off, 64);
            s3 += __shfl_down(s3, off, 64);
        }
        int lane2 = t & 63, wv2 = t >> 6;
        if (lane2 == 0) { wred[wv2][0] = s0; wred[wv2][1] = s1; wred[wv2][2] = s2; wred[wv2][3] = s3; }
        __syncthreads();
        if (t == 0) {
            float sp2   = wred[0][0] + wred[1][0] + wred[2][0] + wred[3][0];
            float st2   = wred[0][1] + wred[1][1] + wred[2][1] + wred[3][1];
            float spt2  = wred[0][2] + wred[1][2] + wred[2][2] + wred[3][2];
            float sbce2 = wred[0][3] + wred[1][3] + wred[2][3] + wred[3][3];
            float sbnd = 0.f;
            #pragma unroll
            for (int bb2 = 0; bb2 < BB; ++bb2) sbnd += bnd[bb2];
            float dice = 1.0f - (2.0f * spt2 + 1e-6f) / (sp2 + st2 + 1e-6f);
            float invN = 1.0f / (float)NPIX;
            float boundary = sbnd * invN;
            float bce = sbce2 * invN;
            float alpha = 0.005f;
            float beta = 0.6f - alpha;      // 0.595
            out[0] = (1.0f - beta) * dice + beta * boundary + 0.4f * bce;
        }
    }
}

extern "C" void kernel_launch(void* const* d_in, const int* in_sizes, int n_in,
                              void* d_out, int out_size, void* d_ws, size_t ws_size,
                              hipStream_t stream) {
    (void)in_sizes; (void)n_in; (void)out_size; (void)ws_size;
    const float* pred = (const float*)d_in[0];
    const float* targ = (const float*)d_in[1];
    unsigned short* zb = (unsigned short*)d_ws;                          // 128 KB
    float* partials = (float*)((char*)d_ws + BB * CH * WW * sizeof(unsigned short));
    unsigned* flag = (unsigned*)((char*)partials + NRB * 8 * sizeof(float));

    zbuild_kernel<<<BB * CH, 64, 0, stream>>>((const float4*)targ, (ushort4*)zb, flag);
    rowmin_fused_kernel<<<NRB, 256, 0, stream>>>(zb, pred, partials, flag, (float*)d_out);
}

// Round 3
// 74.880 us; speedup vs baseline: 1.0571x; 1.0075x over previous
//
#include <hip/hip_runtime.h>
#include <math.h>

#define BB 16
#define HH 256
#define WW 256
#define NPIX (BB*HH*WW)
#define CH 16          // 16-row chunks per column
#define RPC 16
#define ROWS 8         // rows per rowmin block
#define NRB (BB*HH/ROWS)       // 512 rowmin blocks
#define PADW 4
#define GSTRIDE (WW + 2*PADW)  // 264 floats

// ws layout:
//   ushort zb[BB*CH*WW]   (128 KB)  bit r of zb[b,c,j] = (targ[b, c*16+r, j] == 0)
//   float  partials[NRB*8] (16 KB)  per-block {sp,st,spt,sbce,sphip,amax,-,-}
//   unsigned flag          (4 B)    arrival counter (reset by zbuild, no memset dispatch)

// Coherent (cache-maintenance-free) publish/consume helpers.
// Agent-scope relaxed atomics hit the device-coherent point directly: no
// buffer_wbl2 / buffer_inv, so we never pay the deferred writeback of the
// harness's 256 MiB dirty poison fill (that flush cost ~5 us in round 2's
// fence-based protocol).
__device__ __forceinline__ void pub_store(float* p, float v) {
    __hip_atomic_store(p, v, __ATOMIC_RELAXED, __HIP_MEMORY_SCOPE_AGENT);
}
__device__ __forceinline__ float pub_load(const float* p) {
    return __hip_atomic_load(p, __ATOMIC_RELAXED, __HIP_MEMORY_SCOPE_AGENT);
}

// targ -> zero bitmasks. 256 blocks (one 16-row chunk) x 64 threads (4 cols each).
// Block 0 lane 0 also resets the completion counter for the next dispatch.
__global__ __launch_bounds__(64) void zbuild_kernel(const float4* __restrict__ targ4,
                                                    ushort4* __restrict__ zb4,
                                                    unsigned* __restrict__ flag) {
    int blk = blockIdx.x;                 // b*16 + ch ; row offset = blk*16
    int t = threadIdx.x;
    if (blk == 0 && t == 0)
        __hip_atomic_store(flag, 0u, __ATOMIC_RELAXED, __HIP_MEMORY_SCOPE_AGENT);
    const float4* m = targ4 + (size_t)blk * RPC * (WW / 4) + t;
    unsigned z0 = 0, z1 = 0, z2 = 0, z3 = 0;
    #pragma unroll
    for (int r = 0; r < RPC; ++r) {
        float4 v = m[r * (WW / 4)];
        if (v.x == 0.0f) z0 |= 1u << r;
        if (v.y == 0.0f) z1 |= 1u << r;
        if (v.z == 0.0f) z2 |= 1u << r;
        if (v.w == 0.0f) z3 |= 1u << r;
    }
    ushort4 o;
    o.x = (unsigned short)z0; o.y = (unsigned short)z1;
    o.z = (unsigned short)z2; o.w = (unsigned short)z3;
    zb4[blk * (WW / 4) + t] = o;
}

// Fused EDT pass2 + loss partials + last-block final reduction.
// Completion protocol (fence-free): publish record via agent-scope coherent
// stores; bare s_waitcnt vmcnt(0) orders their completion before the relaxed
// arrival increment; 512th arriver reads all records via agent-scope coherent
// loads. No L2 writeback/invalidate instructions anywhere.
__global__ __launch_bounds__(256) void rowmin_fused_kernel(const unsigned short* __restrict__ zb,
                                                           const float* __restrict__ pred,
                                                           float* __restrict__ partials,
                                                           unsigned* __restrict__ flag,
                                                           float* __restrict__ out) {
    int g = blockIdx.x;
    int b = g >> 5;                 // 32 blocks per image
    int r0 = (g & 31) << 3;         // first row-in-image (multiple of 8)
    int C = r0 >> 4;                // chunk containing all 8 rows
    int rb0 = r0 & 15;
    int j = threadIdx.x;

    // stream 16 chunk masks: carries + own-chunk mask, no indexed register array
    int la0 = -1, la1 = -1;         // last zero strictly above chunk C (flavor 0/1)
    int fb0 = 100000, fb1 = 100000; // first zero strictly below chunk C
    unsigned zoc = 0;
    #pragma unroll
    for (int c = 0; c < CH; ++c) {
        unsigned z = (unsigned)zb[((b * CH + c) << 8) + j];
        unsigned zi = (~z) & 0xFFFFu;
        if (c < C) {
            if (z)  la0 = (c << 4) + (31 - __clz(z));
            if (zi) la1 = (c << 4) + (31 - __clz(zi));
        } else if (c > C) {
            if (z  && fb0 == 100000) fb0 = (c << 4) + (__ffs(z) - 1);
            if (zi && fb1 == 100000) fb1 = (c << 4) + (__ffs(zi) - 1);
        } else {
            zoc = z;
        }
    }
    unsigned zoc1 = (~zoc) & 0xFFFFu;

    float x[ROWS];
    #pragma unroll
    for (int r = 0; r < ROWS; ++r)
        x[r] = pred[(((b << 8) + (r0 + r)) << 8) + j];

    __shared__ float gg[ROWS][2][GSTRIDE];   // [0,4) pad | data [4,260) | [260,264) pad
    __shared__ float red[4][8];
    __shared__ float arrF[256][3];
    __shared__ float bnd[BB];
    __shared__ float wred[4][4];
    __shared__ unsigned lastBlk;
    if (j < 2 * ROWS * 2 * PADW) {           // 128 pad slots
        int r = j >> 4, f = (j >> 3) & 1, p = j & 7;
        gg[r][f][(p < PADW) ? p : (WW + p)] = 1e30f;
    }

    #pragma unroll
    for (int r = 0; r < ROWS; ++r) {
        int rb = rb0 + r;
        int i = r0 + r;
        unsigned below = zoc & ((2u << rb) - 1u);
        int lz = below ? ((C << 4) + (31 - __clz(below))) : la0;
        unsigned above = zoc & (0xFFFFu & ~((1u << rb) - 1u));
        int fz = above ? ((C << 4) + (__ffs(above) - 1)) : fb0;
        int da = (lz < 0) ? 100000 : (i - lz);
        int d0 = min(min(da, fz - i), 512);
        float f0 = (float)d0;
        gg[r][0][PADW + j] = f0 * f0;
        unsigned below1 = zoc1 & ((2u << rb) - 1u);
        int lz1 = below1 ? ((C << 4) + (31 - __clz(below1))) : la1;
        unsigned above1 = zoc1 & (0xFFFFu & ~((1u << rb) - 1u));
        int fz1 = above1 ? ((C << 4) + (__ffs(above1) - 1)) : fb1;
        int da1 = (lz1 < 0) ? 100000 : (i - lz1);
        int d1v = min(min(da1, fz1 - i), 512);
        float f1 = (float)d1v;
        gg[r][1][PADW + j] = f1 * f1;
    }
    __syncthreads();

    float sp = 0.f, st = 0.f, spt = 0.f, sbce = 0.f, sphip = 0.f, amax = 0.f;
    #pragma unroll
    for (int r = 0; r < ROWS; ++r) {
        int rb = rb0 + r;
        bool msk = (((zoc >> rb) & 1u) == 0u);    // mask nonzero at this pixel
        const float* bsel = &gg[r][msk ? 0 : 1][0];
        float best = 1e30f;
        #pragma unroll
        for (int c = 0; c <= 2 * PADW; ++c) {
            float Cc = (float)((PADW - c) * (PADW - c));   // == (j-k)^2, k = j-4+c
            best = fminf(best, bsel[j + c] + Cc);
        }
        if (__any(best > 25.0f)) {                // exact fallback (astronomically rare)
            const float* bs = bsel + PADW;
            for (int k = 0; k < WW; ++k) {
                float df = (float)(j - k);
                best = fminf(best, bs[k] + df * df);
            }
        }
        float dd = sqrtf(best);
        float phi = msk ? -dd : dd;               // phi = dist_out - dist_in
        float xr = x[r];
        float ax = fabsf(xr);
        float q = __expf(-ax);
        float pa = 1.0f / (1.0f + q);             // sigmoid(|x|)
        float p = (xr >= 0.0f) ? pa : q * pa;     // sigmoid(x)
        sp += p;
        st += msk ? 1.0f : 0.0f;
        spt += msk ? p : 0.0f;
        sbce += fmaxf(xr, 0.0f) - (msk ? xr : 0.0f) - __logf(pa);  // log1p(e^-|x|) = -log(pa)
        sphip += phi * p;
        amax = fmaxf(amax, fabsf(phi));
    }

    #pragma unroll
    for (int off = 32; off > 0; off >>= 1) {
        sp    += __shfl_down(sp,    off, 64);
        st    += __shfl_down(st,    off, 64);
        spt   += __shfl_down(spt,   off, 64);
        sbce  += __shfl_down(sbce,  off, 64);
        sphip += __shfl_down(sphip, off, 64);
        amax   = fmaxf(amax,  __shfl_down(amax,  off, 64));
    }
    int lane = j & 63, wv = j >> 6;
    if (lane == 0) {
        red[wv][0] = sp; red[wv][1] = st; red[wv][2] = spt; red[wv][3] = sbce;
        red[wv][4] = sphip; red[wv][5] = amax;
    }
    __syncthreads();

    // ---- Completion protocol: coherent publish, counted arrival, no fences ----
    if (j == 0) {
        float* o = partials + (g << 3);
        #pragma unroll
        for (int q2 = 0; q2 < 5; ++q2)
            pub_store(&o[q2], red[0][q2] + red[1][q2] + red[2][q2] + red[3][q2]);
        pub_store(&o[5], fmaxf(fmaxf(red[0][5], red[1][5]), fmaxf(red[2][5], red[3][5])));
        asm volatile("s_waitcnt vmcnt(0)" ::: "memory");   // stores globally visible
        unsigned prev = __hip_atomic_fetch_add(flag, 1u, __ATOMIC_RELAXED,
                                               __HIP_MEMORY_SCOPE_AGENT);
        lastBlk = (prev == (unsigned)(NRB - 1)) ? 1u : 0u;
    }
    __syncthreads();
    if (lastBlk) {
        // all 511 other records visible at the coherent point; read coherently
        int t = j;
        float s0 = 0.f, s1 = 0.f, s2 = 0.f, s3 = 0.f, s4 = 0.f, m5 = 0.f;
        #pragma unroll
        for (int e = 0; e < 2; ++e) {
            const float* rec = partials + (((t << 1) + e) << 3);
            s0 += pub_load(&rec[0]); s1 += pub_load(&rec[1]);
            s2 += pub_load(&rec[2]); s3 += pub_load(&rec[3]);
            s4 += pub_load(&rec[4]);
            m5 = fmaxf(m5, pub_load(&rec[5]));
        }
        arrF[t][0] = s4; arrF[t][1] = m5; arrF[t][2] = s1;   // sphip, amax, st (per-image)
        __syncthreads();
        if (t < 16) {
            float Sb = 0.f, Mb = 0.f, STb = 0.f;
            for (int e = 0; e < 16; ++e) {
                Sb += arrF[t * 16 + e][0];
                Mb = fmaxf(Mb, arrF[t * 16 + e][1]);
                STb += arrF[t * 16 + e][2];
            }
            bnd[t] = (STb > 0.0f) ? (Sb / (Mb + 1e-8f)) : 0.0f;   // jnp.any(mask>0) guard
        }
        #pragma unroll
        for (int off = 32; off > 0; off >>= 1) {
            s0 += __shfl_down(s0, off, 64);
            s1 += __shfl_down(s1, off, 64);
            s2 += __shfl_down(s2, off, 64);
            s3 += __shfl_down(s3, off, 64);
        }
        int lane2 = t & 63, wv2 = t >> 6;
        if (lane2 == 0) { wred[wv2][0] = s0; wred[wv2][1] = s1; wred[wv2][2] = s2; wred[wv2][3] = s3; }
        __syncthreads();
        if (t == 0) {
            float sp2   = wred[0][0] + wred[1][0] + wred[2][0] + wred[3][0];
            float st2   = wred[0][1] + wred[1][1] + wred[2][1] + wred[3][1];
            float spt2  = wred[0][2] + wred[1][2] + wred[2][2] + wred[3][2];
            float sbce2 = wred[0][3] + wred[1][3] + wred[2][3] + wred[3][3];
            float sbnd = 0.f;
            #pragma unroll
            for (int bb2 = 0; bb2 < BB; ++bb2) sbnd += bnd[bb2];
            float dice = 1.0f - (2.0f * spt2 + 1e-6f) / (sp2 + st2 + 1e-6f);
            float invN = 1.0f / (float)NPIX;
            float boundary = sbnd * invN;
            float bce = sbce2 * invN;
            float alpha = 0.005f;
            float beta = 0.6f - alpha;      // 0.595
            out[0] = (1.0f - beta) * dice + beta * boundary + 0.4f * bce;
        }
    }
}

extern "C" void kernel_launch(void* const* d_in, const int* in_sizes, int n_in,
                              void* d_out, int out_size, void* d_ws, size_t ws_size,
                              hipStream_t stream) {
    (void)in_sizes; (void)n_in; (void)out_size; (void)ws_size;
    const float* pred = (const float*)d_in[0];
    const float* targ = (const float*)d_in[1];
    unsigned short* zb = (unsigned short*)d_ws;                          // 128 KB
    float* partials = (float*)((char*)d_ws + BB * CH * WW * sizeof(unsigned short));
    unsigned* flag = (unsigned*)((char*)partials + NRB * 8 * sizeof(float));

    zbuild_kernel<<<BB * CH, 64, 0, stream>>>((const float4*)targ, (ushort4*)zb, flag);
    rowmin_fused_kernel<<<NRB, 256, 0, stream>>>(zb, pred, partials, flag, (float*)d_out);
}

// Round 4
// 71.771 us; speedup vs baseline: 1.1029x; 1.0433x over previous
//
#include <hip/hip_runtime.h>
#include <math.h>

#define BB 16
#define HH 256
#define WW 256
#define NPIX (BB*HH*WW)
#define CH 16          // 16-row chunks per column
#define RPC 16
#define ROWS 8         // rows per rowmin block
#define NRB (BB*HH/ROWS)       // 512 rowmin blocks
#define PADW 4
#define GSTRIDE (WW + 2*PADW)  // 264 floats

// MEASURED-BEST STRUCTURE (3 dispatches). Rounds 1-3 tested every fusion of
// these dispatches (single-kernel + memset: +7.5 us; last-block-done with
// agent fences: +3.7 us; fence-free coherent last-block: +3.2 us). A separate
// 1-block final kernel (~2 us graph-replay launch, warm-L2 loads) beats every
// in-kernel completion protocol on this harness. Do not re-fuse.
//
// ws layout:
//   ushort zb[BB*CH*WW]   (128 KB)  bit r of zb[b,c,j] = (targ[b, c*16+r, j] == 0)
//   float  partials[NRB*8] (16 KB)  per-block {sp,st,spt,sbce,sphip,amax,-,-}

// targ -> zero bitmasks. 256 blocks (one 16-row chunk) x 64 threads (4 cols each).
__global__ __launch_bounds__(64) void zbuild_kernel(const float4* __restrict__ targ4,
                                                    ushort4* __restrict__ zb4) {
    int blk = blockIdx.x;                 // b*16 + ch ; row offset = blk*16
    int t = threadIdx.x;
    const float4* m = targ4 + (size_t)blk * RPC * (WW / 4) + t;
    unsigned z0 = 0, z1 = 0, z2 = 0, z3 = 0;
    #pragma unroll
    for (int r = 0; r < RPC; ++r) {
        float4 v = m[r * (WW / 4)];
        if (v.x == 0.0f) z0 |= 1u << r;
        if (v.y == 0.0f) z1 |= 1u << r;
        if (v.z == 0.0f) z2 |= 1u << r;
        if (v.w == 0.0f) z3 |= 1u << r;
    }
    ushort4 o;
    o.x = (unsigned short)z0; o.y = (unsigned short)z1;
    o.z = (unsigned short)z2; o.w = (unsigned short)z3;
    zb4[blk * (WW / 4) + t] = o;
}

// Fused EDT pass2 + loss partials. One block per 8 rows (within one chunk).
// Column-EDT derived in-register from streamed bitmasks; windowed exact min
// (|j-k|<=4, bound 25: any k outside contributes >= 25, all values exact ints
// in fp32) with per-wave full-scan fallback for worst-case exactness.
__global__ __launch_bounds__(256) void rowmin_fused_kernel(const unsigned short* __restrict__ zb,
                                                           const float* __restrict__ pred,
                                                           float* __restrict__ partials) {
    int g = blockIdx.x;
    int b = g >> 5;                 // 32 blocks per image
    int r0 = (g & 31) << 3;         // first row-in-image (multiple of 8)
    int C = r0 >> 4;                // chunk containing all 8 rows
    int rb0 = r0 & 15;
    int j = threadIdx.x;

    // stream 16 chunk masks: carries + own-chunk mask, no indexed register array
    int la0 = -1, la1 = -1;         // last zero strictly above chunk C (flavor 0/1)
    int fb0 = 100000, fb1 = 100000; // first zero strictly below chunk C
    unsigned zoc = 0;
    #pragma unroll
    for (int c = 0; c < CH; ++c) {
        unsigned z = (unsigned)zb[((b * CH + c) << 8) + j];
        unsigned zi = (~z) & 0xFFFFu;
        if (c < C) {
            if (z)  la0 = (c << 4) + (31 - __clz(z));
            if (zi) la1 = (c << 4) + (31 - __clz(zi));
        } else if (c > C) {
            if (z  && fb0 == 100000) fb0 = (c << 4) + (__ffs(z) - 1);
            if (zi && fb1 == 100000) fb1 = (c << 4) + (__ffs(zi) - 1);
        } else {
            zoc = z;
        }
    }
    unsigned zoc1 = (~zoc) & 0xFFFFu;

    float x[ROWS];
    #pragma unroll
    for (int r = 0; r < ROWS; ++r)
        x[r] = pred[(((b << 8) + (r0 + r)) << 8) + j];

    __shared__ float gg[ROWS][2][GSTRIDE];   // [0,4) pad | data [4,260) | [260,264) pad
    if (j < 2 * ROWS * 2 * PADW) {           // 128 pad slots
        int r = j >> 4, f = (j >> 3) & 1, p = j & 7;
        gg[r][f][(p < PADW) ? p : (WW + p)] = 1e30f;
    }

    #pragma unroll
    for (int r = 0; r < ROWS; ++r) {
        int rb = rb0 + r;
        int i = r0 + r;
        unsigned below = zoc & ((2u << rb) - 1u);
        int lz = below ? ((C << 4) + (31 - __clz(below))) : la0;
        unsigned above = zoc & (0xFFFFu & ~((1u << rb) - 1u));
        int fz = above ? ((C << 4) + (__ffs(above) - 1)) : fb0;
        int da = (lz < 0) ? 100000 : (i - lz);
        int d0 = min(min(da, fz - i), 512);
        float f0 = (float)d0;
        gg[r][0][PADW + j] = f0 * f0;
        unsigned below1 = zoc1 & ((2u << rb) - 1u);
        int lz1 = below1 ? ((C << 4) + (31 - __clz(below1))) : la1;
        unsigned above1 = zoc1 & (0xFFFFu & ~((1u << rb) - 1u));
        int fz1 = above1 ? ((C << 4) + (__ffs(above1) - 1)) : fb1;
        int da1 = (lz1 < 0) ? 100000 : (i - lz1);
        int d1v = min(min(da1, fz1 - i), 512);
        float f1 = (float)d1v;
        gg[r][1][PADW + j] = f1 * f1;
    }
    __syncthreads();

    float sp = 0.f, st = 0.f, spt = 0.f, sbce = 0.f, sphip = 0.f, amax = 0.f;
    #pragma unroll
    for (int r = 0; r < ROWS; ++r) {
        int rb = rb0 + r;
        bool msk = (((zoc >> rb) & 1u) == 0u);    // mask nonzero at this pixel
        const float* bsel = &gg[r][msk ? 0 : 1][0];
        float best = 1e30f;
        #pragma unroll
        for (int c = 0; c <= 2 * PADW; ++c) {
            float Cc = (float)((PADW - c) * (PADW - c));   // == (j-k)^2, k = j-4+c
            best = fminf(best, bsel[j + c] + Cc);
        }
        if (__any(best > 25.0f)) {                // exact fallback (astronomically rare)
            const float* bs = bsel + PADW;
            for (int k = 0; k < WW; ++k) {
                float df = (float)(j - k);
                best = fminf(best, bs[k] + df * df);
            }
        }
        float dd = sqrtf(best);
        float phi = msk ? -dd : dd;               // phi = dist_out - dist_in
        float xr = x[r];
        float ax = fabsf(xr);
        float q = __expf(-ax);
        float pa = 1.0f / (1.0f + q);             // sigmoid(|x|)
        float p = (xr >= 0.0f) ? pa : q * pa;     // sigmoid(x)
        sp += p;
        st += msk ? 1.0f : 0.0f;
        spt += msk ? p : 0.0f;
        sbce += fmaxf(xr, 0.0f) - (msk ? xr : 0.0f) - __logf(pa);  // log1p(e^-|x|) = -log(pa)
        sphip += phi * p;
        amax = fmaxf(amax, fabsf(phi));
    }

    #pragma unroll
    for (int off = 32; off > 0; off >>= 1) {
        sp    += __shfl_down(sp,    off, 64);
        st    += __shfl_down(st,    off, 64);
        spt   += __shfl_down(spt,   off, 64);
        sbce  += __shfl_down(sbce,  off, 64);
        sphip += __shfl_down(sphip, off, 64);
        amax   = fmaxf(amax,  __shfl_down(amax,  off, 64));
    }
    __shared__ float red[4][8];
    int lane = j & 63, wv = j >> 6;
    if (lane == 0) {
        red[wv][0] = sp; red[wv][1] = st; red[wv][2] = spt; red[wv][3] = sbce;
        red[wv][4] = sphip; red[wv][5] = amax;
    }
    __syncthreads();
    if (j == 0) {
        float* o = partials + g * 8;
        #pragma unroll
        for (int q2 = 0; q2 < 5; ++q2)
            o[q2] = red[0][q2] + red[1][q2] + red[2][q2] + red[3][q2];
        o[5] = fmaxf(fmaxf(red[0][5], red[1][5]), fmaxf(red[2][5], red[3][5]));
    }
}

// Single-block final reduction: 512 records -> loss scalar.
// Per-image "any mask pixel" guard derived from the per-image st sum.
__global__ __launch_bounds__(256) void final_kernel(const float* __restrict__ partials,
                                                    float* __restrict__ out) {
    int t = threadIdx.x;
    // 32 records per image; thread t reads records 2t, 2t+1 (both image t>>4)
    float s0 = 0.f, s1 = 0.f, s2 = 0.f, s3 = 0.f, s4 = 0.f, m5 = 0.f;
    #pragma unroll
    for (int e = 0; e < 2; ++e) {
        const float* rec = partials + ((t * 2 + e) << 3);
        s0 += rec[0]; s1 += rec[1]; s2 += rec[2]; s3 += rec[3];
        s4 += rec[4];
        m5 = fmaxf(m5, rec[5]);
    }
    __shared__ float arr[256][3];
    arr[t][0] = s4; arr[t][1] = m5; arr[t][2] = s1;   // sphip, amax, st (per-image pieces)
    __syncthreads();
    __shared__ float bnd[16];
    if (t < 16) {
        float Sb = 0.f, Mb = 0.f, STb = 0.f;
        for (int e = 0; e < 16; ++e) {
            Sb += arr[t * 16 + e][0];
            Mb = fmaxf(Mb, arr[t * 16 + e][1]);
            STb += arr[t * 16 + e][2];
        }
        // jnp.any(mask>0) == (count of mask pixels > 0)
        bnd[t] = (STb > 0.0f) ? (Sb / (Mb + 1e-8f)) : 0.0f;
    }
    #pragma unroll
    for (int off = 32; off > 0; off >>= 1) {
        s0 += __shfl_down(s0, off, 64);
        s1 += __shfl_down(s1, off, 64);
        s2 += __shfl_down(s2, off, 64);
        s3 += __shfl_down(s3, off, 64);
    }
    __shared__ float wred[4][4];
    int lane = t & 63, wv = t >> 6;
    if (lane == 0) { wred[wv][0] = s0; wred[wv][1] = s1; wred[wv][2] = s2; wred[wv][3] = s3; }
    __syncthreads();
    if (t == 0) {
        float sp   = wred[0][0] + wred[1][0] + wred[2][0] + wred[3][0];
        float st   = wred[0][1] + wred[1][1] + wred[2][1] + wred[3][1];
        float spt  = wred[0][2] + wred[1][2] + wred[2][2] + wred[3][2];
        float sbce = wred[0][3] + wred[1][3] + wred[2][3] + wred[3][3];
        float sbnd = 0.f;
        #pragma unroll
        for (int bb2 = 0; bb2 < BB; ++bb2) sbnd += bnd[bb2];
        float dice = 1.0f - (2.0f * spt + 1e-6f) / (sp + st + 1e-6f);
        float invN = 1.0f / (float)NPIX;
        float boundary = sbnd * invN;
        float bce = sbce * invN;
        float alpha = 0.005f;
        float beta = 0.6f - alpha;      // 0.595
        out[0] = (1.0f - beta) * dice + beta * boundary + 0.4f * bce;
    }
}

extern "C" void kernel_launch(void* const* d_in, const int* in_sizes, int n_in,
                              void* d_out, int out_size, void* d_ws, size_t ws_size,
                              hipStream_t stream) {
    (void)in_sizes; (void)n_in; (void)out_size; (void)ws_size;
    const float* pred = (const float*)d_in[0];
    const float* targ = (const float*)d_in[1];
    unsigned short* zb = (unsigned short*)d_ws;   // 128 KB
    float* partials = (float*)((char*)d_ws + BB * CH * WW * sizeof(unsigned short));

    zbuild_kernel<<<BB * CH, 64, 0, stream>>>((const float4*)targ, (ushort4*)zb);
    rowmin_fused_kernel<<<NRB, 256, 0, stream>>>(zb, pred, partials);
    final_kernel<<<1, 256, 0, stream>>>(partials, (float*)d_out);
}